// Round 1
// baseline (23537.999 us; speedup 1.0000x reference)
//
#include <hip/hip_runtime.h>
#include <hip/hip_cooperative_groups.h>
#include <cstdint>
#include <cstddef>

#define NENV 4096
#define SEQ  128
#define LATENT 64
#define EMB  256
#define HID  1024
#define SA   2

namespace cg = cooperative_groups;

typedef _Float16 half8 __attribute__((ext_vector_type(8)));
typedef float f32x4 __attribute__((ext_vector_type(4)));

// assembler-encoded partial drain: wait until <= n vector-mem ops outstanding
#define WAITVM(n) asm volatile("s_waitcnt vmcnt(" #n ")" ::: "memory")
#define BARRIER() { __builtin_amdgcn_s_barrier(); asm volatile("" ::: "memory"); }

__device__ __forceinline__ float sigmoid_f(float x){ return 1.0f/(1.0f + __expf(-x)); }

__device__ __forceinline__ void dma16(const void* g, void* l){
  __builtin_amdgcn_global_load_lds(
      (const __attribute__((address_space(1))) void*)g,
      (__attribute__((address_space(3))) void*)l, 16, 0, 0);
}

__device__ __forceinline__ f32x4 mfma16(half8 a, half8 b, f32x4 c){
  return __builtin_amdgcn_mfma_f32_16x16x32_f16(a, b, c, 0, 0, 0);
}

// bank swizzle: element [row R][seg s] lives at slot R*4 + ((s + R + (R>>2)) & 3)
// -> DMA slot R*4+p holds seg (p - R - (R>>2)) & 3   (same 64B line, permuted)
__device__ __forceinline__ int seg_for_slot(int R, int p){ return (p - R - (R >> 2)) & 3; }
__device__ __forceinline__ int phys_slot(int R, int q){ return R*4 + ((q + R + (R >> 2)) & 3); }

// ---------- shared-memory overlay: max of the three phase footprints (60 KB) ----------
struct THMem {
  float w2s[32*256];   // 32 KB
  float w1s[66*32];    // 8.4 KB
  float zs[8][64];
  float x1s[8][32];
  float sts[8][2];
};
union SMem {
  half8 gbuf[3*1280];  // 60 KB: GRU staging (3 bufs x (512 A-slots + 3*256 B-slots))
  half8 obuf[3*512];   // 24 KB: out1 staging
  THMem th;            // ~44 KB: tail/head MLP
};

// ---------- pre-pass: transpose + fp32->fp16: in [K][C] -> out [C][K] ----------
__global__ void transpose_cvt_kernel(const float* __restrict__ in, _Float16* __restrict__ out,
                                     int K, int C){
  int n = K*C;
  for (int i = blockIdx.x*blockDim.x + threadIdx.x; i < n; i += gridDim.x*blockDim.x){
    int c = i / K;
    int k = i - c*K;
    out[i] = (_Float16)in[(size_t)k*C + c];
  }
}

__global__ void init_h_kernel(const float* __restrict__ rnn, _Float16* __restrict__ h16){
  int n = NENV*HID;
  for (int i = blockIdx.x*blockDim.x + threadIdx.x; i < n; i += gridDim.x*blockDim.x){
    h16[i] = (_Float16)rnn[i];
  }
}

// ---------- fused GRU GEMM phase: 128 rows x 64 h-cols x 3 gates, BK=32, depth-2 pipeline ----------
template<int K, int NIT>
__device__ __forceinline__ void gru_phase(
    const _Float16* __restrict__ A, const _Float16* __restrict__ W,
    int r0, int c0, int tid, int wave,
    const int* pa, int pb, half8* sBuf,
    f32x4* accR, f32x4* accZ, f32x4* accN)
{
  const int RA0 = tid >> 2,        PA0 = tid & 3;
  const int RA1 = 64 + (tid >> 2), PA1 = tid & 3;
  const int RB  = tid >> 2,        PB  = tid & 3;
  const _Float16* gA0 = A + (size_t)(r0 + RA0)*K + seg_for_slot(RA0, PA0)*8;
  const _Float16* gA1 = A + (size_t)(r0 + RA1)*K + seg_for_slot(RA1, PA1)*8;
  const int sgb = seg_for_slot(RB, PB);
  const _Float16* gB0 = W + (size_t)(0*HID + c0 + RB)*K + sgb*8;
  const _Float16* gB1 = W + (size_t)(1*HID + c0 + RB)*K + sgb*8;
  const _Float16* gB2 = W + (size_t)(2*HID + c0 + RB)*K + sgb*8;

  auto issue = [&](int bi){
    char* base = (char*)sBuf + (size_t)bi*1280*16;
    dma16(gA0, base + (size_t)(0    + wave*64)*16);
    dma16(gA1, base + (size_t)(256  + wave*64)*16);
    dma16(gB0, base + (size_t)(512  + wave*64)*16);
    dma16(gB1, base + (size_t)(768  + wave*64)*16);
    dma16(gB2, base + (size_t)(1024 + wave*64)*16);
    gA0 += 32; gA1 += 32; gB0 += 32; gB1 += 32; gB2 += 32;
  };

  issue(0); issue(1);
#pragma unroll
  for (int it = 0; it < NIT; ++it){
    if (it < NIT - 1) { WAITVM(5); } else { WAITVM(0); }
    BARRIER();
    if (it + 2 < NIT) issue((it + 2) % 3);
    const half8* buf = sBuf + (it % 3)*1280;
    half8 b0 = buf[512  + pb];
    half8 b1 = buf[768  + pb];
    half8 b2 = buf[1024 + pb];
#pragma unroll
    for (int mt = 0; mt < 8; ++mt){
      half8 a = buf[pa[mt]];
      accR[mt] = mfma16(a, b0, accR[mt]);
      accZ[mt] = mfma16(a, b1, accZ[mt]);
      accN[mt] = mfma16(a, b2, accN[mt]);
    }
  }
  __syncthreads();   // all waves done with buffers before next phase reuses them
}

// ---------- phase A: GRU cell (both GEMMs + gate nonlinearity) for one 128x64 tile ----------
__device__ __forceinline__ void phaseA(
    int vb, const _Float16* __restrict__ x2h, const _Float16* __restrict__ hcur,
    const _Float16* __restrict__ wihT, const _Float16* __restrict__ whhT,
    const float* __restrict__ bih, const float* __restrict__ bhh,
    _Float16* __restrict__ hnxt, float* __restrict__ hout, half8* sBuf)
{
  const int tid = threadIdx.x;
  const int lane = tid & 63, wave = tid >> 6;
  const int m = lane & 15, q = lane >> 4, n0 = wave*16;

  // XCD swizzle: XCD x owns colgroups {2x, 2x+1} -> W slice L2-resident
  const int colg = (vb & 7)*2 + ((vb >> 3) & 1);
  const int rowg = vb >> 4;            // 0..31
  const int r0 = rowg*128, c0 = colg*64;

  int pa[8];
#pragma unroll
  for (int mt = 0; mt < 8; ++mt) pa[mt] = phys_slot(mt*16 + m, q);
  const int pb = phys_slot(n0 + m, q);

  f32x4 accR[8], accZ[8], accNi[8], accNh[8];
#pragma unroll
  for (int i = 0; i < 8; ++i){
    accR[i] = (f32x4){0.f,0.f,0.f,0.f};
    accZ[i] = (f32x4){0.f,0.f,0.f,0.f};
    accNi[i] = (f32x4){0.f,0.f,0.f,0.f};
    accNh[i] = (f32x4){0.f,0.f,0.f,0.f};
  }

  gru_phase<EMB, EMB/32>(x2h,  wihT, r0, c0, tid, wave, pa, pb, sBuf, accR, accZ, accNi);
  gru_phase<HID, HID/32>(hcur, whhT, r0, c0, tid, wave, pa, pb, sBuf, accR, accZ, accNh);

  const int gc = c0 + n0 + m;
  const float b_r  = bih[gc]         + bhh[gc];
  const float b_z  = bih[gc + HID]   + bhh[gc + HID];
  const float b_in = bih[gc + 2*HID];
  const float b_hn = bhh[gc + 2*HID];
#pragma unroll
  for (int mt = 0; mt < 8; ++mt){
#pragma unroll
    for (int r = 0; r < 4; ++r){
      int grow = r0 + mt*16 + q*4 + r;
      float rr = sigmoid_f(accR[mt][r] + b_r);
      float u  = sigmoid_f(accZ[mt][r] + b_z);
      float nn = tanhf(accNi[mt][r] + b_in + rr*(accNh[mt][r] + b_hn));
      size_t idx = (size_t)grow*HID + gc;
      float hold = (float)hcur[idx];
      float hnew = (1.0f - u)*nn + u*hold;
      hnxt[idx] = (_Float16)hnew;
      if (hout) hout[idx] = hnew;
    }
  }
}

// ---------- phase B: o1 = relu(h @ w3 + b3) -> fp16, one 64x64 tile, BK=32, pipelined ----------
__device__ __forceinline__ void phaseB(
    int vb, const _Float16* __restrict__ h16, const _Float16* __restrict__ w3T,
    const float* __restrict__ b3, _Float16* __restrict__ o1, half8* sBuf)
{
  const int tid = threadIdx.x;
  const int lane = tid & 63, wave = tid >> 6;
  const int m = lane & 15, q = lane >> 4, n0 = wave*16;

  const int colg = vb & 7;     // XCD x owns col slice x (w3T slice 128 KB L2-resident)
  const int rowg = vb >> 3;    // 0..63
  const int r0 = rowg*64, c0 = colg*64;

  int pa[4];
#pragma unroll
  for (int mt = 0; mt < 4; ++mt) pa[mt] = phys_slot(mt*16 + m, q);
  const int pb = phys_slot(n0 + m, q);

  f32x4 acc[4];
#pragma unroll
  for (int i = 0; i < 4; ++i) acc[i] = (f32x4){0.f,0.f,0.f,0.f};

  const int R = tid >> 2, P = tid & 3;
  const int sg = seg_for_slot(R, P);
  const _Float16* gA = h16 + (size_t)(r0 + R)*HID + sg*8;
  const _Float16* gB = w3T + (size_t)(c0 + R)*HID + sg*8;

  auto issue = [&](int bi){
    char* base = (char*)sBuf + (size_t)bi*512*16;
    dma16(gA, base + (size_t)(0   + wave*64)*16);
    dma16(gB, base + (size_t)(256 + wave*64)*16);
    gA += 32; gB += 32;
  };

  issue(0); issue(1);
#pragma unroll
  for (int it = 0; it < 32; ++it){
    if (it < 31) { WAITVM(2); } else { WAITVM(0); }
    BARRIER();
    if (it + 2 < 32) issue((it + 2) % 3);
    const half8* buf = sBuf + (it % 3)*512;
    half8 b = buf[256 + pb];
#pragma unroll
    for (int mt = 0; mt < 4; ++mt){
      half8 a = buf[pa[mt]];
      acc[mt] = mfma16(a, b, acc[mt]);
    }
  }
  __syncthreads();

  const int gc = c0 + n0 + m;
  const float bb = b3[gc];
#pragma unroll
  for (int mt = 0; mt < 4; ++mt){
#pragma unroll
    for (int r = 0; r < 4; ++r){
      int grow = r0 + mt*16 + q*4 + r;
      o1[(size_t)grow*(HID/2) + gc] = (_Float16)fmaxf(acc[mt][r] + bb, 0.f);
    }
  }
}

// ---------- phase C: tail of step t (o1@w4, tanh, out) + head of step t+1 (mlp_in -> x2h) ----------
// mode 0: init (state=-2, x2h for t=0); mode 1: mid; mode 2: last (tail only). 8 rows per tile.
__device__ __forceinline__ void phaseC(
    int vb, int t, int mode,
    const _Float16* __restrict__ o1, const float* __restrict__ w4, const float* __restrict__ b4,
    const float* __restrict__ z,  const float* __restrict__ w1, const float* __restrict__ b1,
    const float* __restrict__ w2, const float* __restrict__ b2,
    _Float16* __restrict__ x2h, float* __restrict__ out, THMem& th)
{
  const int tid = threadIdx.x;
  const int r0 = vb*8;

  if (mode != 2){
    for (int i = tid; i < 66*32; i += 256) th.w1s[i] = w1[i];
    for (int i = tid; i < 32*256; i += 256) th.w2s[i] = w2[i];
    int zt = (mode == 0) ? 0 : (t + 1);
    for (int i = tid; i < 8*64; i += 256){
      int r = i >> 6, k = i & 63;
      th.zs[r][k] = z[(size_t)(r0 + r)*SEQ*LATENT + zt*LATENT + k];
    }
  }

  if (mode != 0){
    int r = tid >> 5, p = tid & 31;           // 8 rows x 32 lanes
    const _Float16* orow = o1 + (size_t)(r0 + r)*(HID/2);
    float a0 = 0.f, a1 = 0.f;
    for (int k = p*16; k < p*16 + 16; ++k){
      float v = (float)orow[k];
      a0 += v*w4[k*2];
      a1 += v*w4[k*2 + 1];
    }
#pragma unroll
    for (int off = 1; off < 32; off <<= 1){
      a0 += __shfl_xor(a0, off);
      a1 += __shfl_xor(a1, off);
    }
    if (p == 0){
      a0 = tanhf(a0 + b4[0]);
      a1 = tanhf(a1 + b4[1]);
      out[(size_t)(r0 + r)*SEQ*SA + t*SA + 0] = a0;
      out[(size_t)(r0 + r)*SEQ*SA + t*SA + 1] = a1;
      th.sts[r][0] = a0; th.sts[r][1] = a1;
    }
  } else {
    if (tid < 16) th.sts[tid >> 1][tid & 1] = -2.0f;
  }
  __syncthreads();

  if (mode != 2){
    {
      int r = tid >> 5, j = tid & 31;         // 8 rows x 32 cols = 256 threads
      float acc = b1[j];
      acc += th.sts[r][0]*th.w1s[0*32 + j] + th.sts[r][1]*th.w1s[1*32 + j];
#pragma unroll 8
      for (int k = 0; k < 64; ++k) acc += th.zs[r][k]*th.w1s[(k + 2)*32 + j];
      th.x1s[r][j] = fmaxf(acc, 0.f);
    }
    __syncthreads();
    int col = tid;
    for (int r = 0; r < 8; ++r){
      float acc = b2[col];
#pragma unroll
      for (int k = 0; k < 32; ++k) acc += th.x1s[r][k]*th.w2s[k*256 + col];
      x2h[(size_t)(r0 + r)*EMB + col] = (_Float16)fmaxf(acc, 0.f);
    }
  }
  __syncthreads();
}

// ---------- persistent cooperative kernel: entire 128-step recurrence in one dispatch ----------
__global__ __launch_bounds__(256, 2) void fused_seq_kernel(
    const float* __restrict__ z,
    const _Float16* __restrict__ wihT, const _Float16* __restrict__ whhT,
    const float* __restrict__ bih, const float* __restrict__ bhh,
    const _Float16* __restrict__ w3T, const float* __restrict__ b3,
    const float* __restrict__ w4, const float* __restrict__ b4,
    const float* __restrict__ w1, const float* __restrict__ b1,
    const float* __restrict__ w2, const float* __restrict__ b2,
    _Float16* __restrict__ h16a, _Float16* __restrict__ h16b,
    _Float16* __restrict__ x2h, _Float16* __restrict__ o1,
    float* __restrict__ out, float* __restrict__ hfinal)
{
  __shared__ SMem sm;
  cg::grid_group grid = cg::this_grid();
  const int nb = (int)gridDim.x;   // 256 or 512; both divide 512 -> uniform trip counts

  // initial head: x2h for t=0 from state=-2 and z_0
  for (int vb = blockIdx.x; vb < NENV/8; vb += nb)
    phaseC(vb, 0, 0, o1, w4, b4, z, w1, b1, w2, b2, x2h, out, sm.th);
  grid.sync();

  for (int t = 0; t < SEQ; ++t){
    const _Float16* hc = (t & 1) ? h16b : h16a;
    _Float16* hn = (t & 1) ? h16a : h16b;

    for (int vb = blockIdx.x; vb < 512; vb += nb)
      phaseA(vb, x2h, hc, wihT, whhT, bih, bhh, hn,
             (t == SEQ - 1) ? hfinal : nullptr, sm.gbuf);
    grid.sync();

    for (int vb = blockIdx.x; vb < 512; vb += nb)
      phaseB(vb, hn, w3T, b3, o1, sm.obuf);
    grid.sync();

    const int mode = (t < SEQ - 1) ? 1 : 2;
    for (int vb = blockIdx.x; vb < NENV/8; vb += nb)
      phaseC(vb, t, mode, o1, w4, b4, z, w1, b1, w2, b2, x2h, out, sm.th);
    if (t < SEQ - 1) grid.sync();
  }
}

// ---------- fallback wrappers (used only if cooperative launch is unavailable) ----------
__global__ __launch_bounds__(256, 2) void gru_kernel(
    const _Float16* __restrict__ x2h, const _Float16* __restrict__ hcur,
    const _Float16* __restrict__ wihT, const _Float16* __restrict__ whhT,
    const float* __restrict__ bih, const float* __restrict__ bhh,
    _Float16* __restrict__ hnxt, float* __restrict__ hout)
{
  __shared__ SMem sm;
  phaseA(blockIdx.x, x2h, hcur, wihT, whhT, bih, bhh, hnxt, hout, sm.gbuf);
}

__global__ __launch_bounds__(256, 2) void out1_kernel(
    const _Float16* __restrict__ h16, const _Float16* __restrict__ w3T,
    const float* __restrict__ b3, _Float16* __restrict__ o1)
{
  __shared__ SMem sm;
  phaseB(blockIdx.x, h16, w3T, b3, o1, sm.obuf);
}

__global__ void tail_head_kernel(
    const _Float16* __restrict__ o1, const float* __restrict__ w4, const float* __restrict__ b4,
    const float* __restrict__ z,  const float* __restrict__ w1, const float* __restrict__ b1,
    const float* __restrict__ w2, const float* __restrict__ b2,
    _Float16* __restrict__ x2h, float* __restrict__ out, int t, int mode)
{
  __shared__ SMem sm;
  phaseC(blockIdx.x, t, mode, o1, w4, b4, z, w1, b1, w2, b2, x2h, out, sm.th);
}

extern "C" void kernel_launch(void* const* d_in, const int* in_sizes, int n_in,
                              void* d_out, int out_size, void* d_ws, size_t ws_size,
                              hipStream_t stream) {
  const float* z   = (const float*)d_in[0];
  const float* rnn = (const float*)d_in[1];
  const float* w1  = (const float*)d_in[2];
  const float* b1  = (const float*)d_in[3];
  const float* w2  = (const float*)d_in[4];
  const float* b2  = (const float*)d_in[5];
  const float* wih = (const float*)d_in[6];
  const float* bih = (const float*)d_in[7];
  const float* whh = (const float*)d_in[8];
  const float* bhh = (const float*)d_in[9];
  const float* w3  = (const float*)d_in[10];
  const float* b3  = (const float*)d_in[11];
  const float* w4  = (const float*)d_in[12];
  const float* b4  = (const float*)d_in[13];
  float* out = (float*)d_out;

  char* ws = (char*)d_ws;
  _Float16* wihT = (_Float16*)ws;                 ws += (size_t)3*HID*EMB*2;
  _Float16* whhT = (_Float16*)ws;                 ws += (size_t)3*HID*HID*2;
  _Float16* w3T  = (_Float16*)ws;                 ws += (size_t)(HID/2)*HID*2;
  _Float16* h16a = (_Float16*)ws;                 ws += (size_t)NENV*HID*2;
  _Float16* h16b = (_Float16*)ws;                 ws += (size_t)NENV*HID*2;
  _Float16* x2h  = (_Float16*)ws;                 ws += (size_t)NENV*EMB*2;
  _Float16* o1   = (_Float16*)ws;                 ws += (size_t)NENV*(HID/2)*2;

  transpose_cvt_kernel<<<512, 256, 0, stream>>>(wih, wihT, EMB, 3*HID);
  transpose_cvt_kernel<<<1024, 256, 0, stream>>>(whh, whhT, HID, 3*HID);
  transpose_cvt_kernel<<<256, 256, 0, stream>>>(w3, w3T, HID, HID/2);
  init_h_kernel<<<1024, 256, 0, stream>>>(rnn, h16a);

  float* hfinal = out + (size_t)NENV*SEQ*SA;

  // co-residency: 2 blocks/CU expected (60KB LDS, <=256 VGPR). Virtualized over 512
  // tiles, so grid=256 (1 block/CU) is also correct if occupancy drops.
  int maxPerCU = 0;
  hipError_t occErr = hipOccupancyMaxActiveBlocksPerMultiprocessor(
      &maxPerCU, (const void*)fused_seq_kernel, 256, 0);
  int grid = 0;
  if (occErr == hipSuccess && maxPerCU >= 2) grid = 512;
  else if (occErr == hipSuccess && maxPerCU == 1) grid = 256;

  bool coop_ok = false;
  if (grid > 0){
    void* args[] = { (void*)&z, (void*)&wihT, (void*)&whhT, (void*)&bih, (void*)&bhh,
                     (void*)&w3T, (void*)&b3, (void*)&w4, (void*)&b4,
                     (void*)&w1, (void*)&b1, (void*)&w2, (void*)&b2,
                     (void*)&h16a, (void*)&h16b, (void*)&x2h, (void*)&o1,
                     (void*)&out, (void*)&hfinal };
    hipError_t e = hipLaunchCooperativeKernel((const void*)fused_seq_kernel,
                                              dim3(grid), dim3(256), args, 0, stream);
    coop_ok = (e == hipSuccess);
  }

  if (!coop_ok){
    // fallback: original 3-kernel-per-step loop (identical phase code)
    tail_head_kernel<<<NENV/8, 256, 0, stream>>>(o1, w4, b4, z, w1, b1, w2, b2, x2h, out, 0, 0);
    for (int t = 0; t < SEQ; ++t){
      _Float16* hc = (t & 1) ? h16b : h16a;
      _Float16* hn = (t & 1) ? h16a : h16b;
      gru_kernel<<<512, 256, 0, stream>>>(x2h, hc, wihT, whhT, bih, bhh, hn,
                                          (t == SEQ - 1) ? hfinal : nullptr);
      out1_kernel<<<512, 256, 0, stream>>>(hn, w3T, b3, o1);
      tail_head_kernel<<<NENV/8, 256, 0, stream>>>(o1, w4, b4, z, w1, b1, w2, b2, x2h, out,
                                                   t, (t < SEQ - 1) ? 1 : 2);
    }
  }
}

// Round 2
// 10572.149 us; speedup vs baseline: 2.2264x; 2.2264x over previous
//
#include <hip/hip_runtime.h>
#include <cstdint>
#include <cstddef>

#define NENV 4096
#define SEQ  128
#define LATENT 64
#define EMB  256
#define HID  1024
#define SA   2

typedef _Float16 half8 __attribute__((ext_vector_type(8)));
typedef float f32x4 __attribute__((ext_vector_type(4)));

// assembler-encoded partial drain: wait until <= n vector-mem ops outstanding
#define WAITVM(n) asm volatile("s_waitcnt vmcnt(" #n ")" ::: "memory")
#define BARRIER() { __builtin_amdgcn_s_barrier(); asm volatile("" ::: "memory"); }

__device__ __forceinline__ float sigmoid_f(float x){ return 1.0f/(1.0f + __expf(-x)); }

__device__ __forceinline__ void dma16(const void* g, void* l){
  __builtin_amdgcn_global_load_lds(
      (const __attribute__((address_space(1))) void*)g,
      (__attribute__((address_space(3))) void*)l, 16, 0, 0);
}

__device__ __forceinline__ f32x4 mfma16(half8 a, half8 b, f32x4 c){
  return __builtin_amdgcn_mfma_f32_16x16x32_f16(a, b, c, 0, 0, 0);
}

// bank swizzle: element [row R][seg s] lives at slot R*4 + ((s + R + (R>>2)) & 3)
// -> DMA slot R*4+p holds seg (p - R - (R>>2)) & 3   (same 64B line, permuted)
__device__ __forceinline__ int seg_for_slot(int R, int p){ return (p - R - (R >> 2)) & 3; }
__device__ __forceinline__ int phys_slot(int R, int q){ return R*4 + ((q + R + (R >> 2)) & 3); }

// ---------- pre-pass: transpose + fp32->fp16: in [K][C] -> out [C][K] ----------
__global__ void transpose_cvt_kernel(const float* __restrict__ in, _Float16* __restrict__ out,
                                     int K, int C){
  int n = K*C;
  for (int i = blockIdx.x*blockDim.x + threadIdx.x; i < n; i += gridDim.x*blockDim.x){
    int c = i / K;
    int k = i - c*K;
    out[i] = (_Float16)in[(size_t)k*C + c];
  }
}

__global__ void init_h_kernel(const float* __restrict__ rnn, _Float16* __restrict__ h16){
  int n = NENV*HID;
  for (int i = blockIdx.x*blockDim.x + threadIdx.x; i < n; i += gridDim.x*blockDim.x){
    h16[i] = (_Float16)rnn[i];
  }
}

// ---------- fused GRU: 128 rows x 64 h-cols x 3 gates, BK=32, pipelined depth-2 ----------
// (verbatim from the verified 9895us kernel)
template<int K, int NIT>
__device__ __forceinline__ void gru_phase(
    const _Float16* __restrict__ A, const _Float16* __restrict__ W,
    int r0, int c0, int tid, int wave,
    const int* pa, int pb, half8* sBuf,
    f32x4* accR, f32x4* accZ, f32x4* accN)
{
  const int RA0 = tid >> 2,        PA0 = tid & 3;
  const int RA1 = 64 + (tid >> 2), PA1 = tid & 3;
  const int RB  = tid >> 2,        PB  = tid & 3;
  const _Float16* gA0 = A + (size_t)(r0 + RA0)*K + seg_for_slot(RA0, PA0)*8;
  const _Float16* gA1 = A + (size_t)(r0 + RA1)*K + seg_for_slot(RA1, PA1)*8;
  const int sgb = seg_for_slot(RB, PB);
  const _Float16* gB0 = W + (size_t)(0*HID + c0 + RB)*K + sgb*8;
  const _Float16* gB1 = W + (size_t)(1*HID + c0 + RB)*K + sgb*8;
  const _Float16* gB2 = W + (size_t)(2*HID + c0 + RB)*K + sgb*8;

  auto issue = [&](int bi){
    char* base = (char*)sBuf + (size_t)bi*1280*16;
    dma16(gA0, base + (size_t)(0    + wave*64)*16);
    dma16(gA1, base + (size_t)(256  + wave*64)*16);
    dma16(gB0, base + (size_t)(512  + wave*64)*16);
    dma16(gB1, base + (size_t)(768  + wave*64)*16);
    dma16(gB2, base + (size_t)(1024 + wave*64)*16);
    gA0 += 32; gA1 += 32; gB0 += 32; gB1 += 32; gB2 += 32;
  };

  issue(0); issue(1);
#pragma unroll
  for (int it = 0; it < NIT; ++it){
    if (it < NIT - 1) { WAITVM(5); } else { WAITVM(0); }
    BARRIER();
    if (it + 2 < NIT) issue((it + 2) % 3);
    const half8* buf = sBuf + (it % 3)*1280;
    half8 b0 = buf[512  + pb];
    half8 b1 = buf[768  + pb];
    half8 b2 = buf[1024 + pb];
#pragma unroll
    for (int mt = 0; mt < 8; ++mt){
      half8 a = buf[pa[mt]];
      accR[mt] = mfma16(a, b0, accR[mt]);
      accZ[mt] = mfma16(a, b1, accZ[mt]);
      accN[mt] = mfma16(a, b2, accN[mt]);
    }
  }
  __syncthreads();   // all waves done with buffers before next phase reuses them
}

__global__ __launch_bounds__(256, 2) void gru_kernel(
    const _Float16* __restrict__ x2h, const _Float16* __restrict__ hcur,
    const _Float16* __restrict__ wihT, const _Float16* __restrict__ whhT,
    const float* __restrict__ bih, const float* __restrict__ bhh,
    _Float16* __restrict__ hnxt, float* __restrict__ hout)
{
  __shared__ half8 sBuf[3*1280];   // 60 KB
  const int tid = threadIdx.x;
  const int lane = tid & 63, wave = tid >> 6;
  const int m = lane & 15, q = lane >> 4, n0 = wave*16;

  // XCD swizzle: XCD x owns colgroups {2x, 2x+1} -> W slice L2-resident, h shared within XCD
  const int id = blockIdx.x;
  const int colg = (id & 7)*2 + ((id >> 3) & 1);
  const int rowg = id >> 4;            // 0..31
  const int r0 = rowg*128, c0 = colg*64;

  int pa[8];
#pragma unroll
  for (int mt = 0; mt < 8; ++mt) pa[mt] = phys_slot(mt*16 + m, q);
  const int pb = phys_slot(n0 + m, q);

  f32x4 accR[8], accZ[8], accNi[8], accNh[8];
#pragma unroll
  for (int i = 0; i < 8; ++i){
    accR[i] = (f32x4){0.f,0.f,0.f,0.f};
    accZ[i] = (f32x4){0.f,0.f,0.f,0.f};
    accNi[i] = (f32x4){0.f,0.f,0.f,0.f};
    accNh[i] = (f32x4){0.f,0.f,0.f,0.f};
  }

  gru_phase<EMB, EMB/32>(x2h,  wihT, r0, c0, tid, wave, pa, pb, sBuf, accR, accZ, accNi);
  gru_phase<HID, HID/32>(hcur, whhT, r0, c0, tid, wave, pa, pb, sBuf, accR, accZ, accNh);

  const int gc = c0 + n0 + m;
  const float b_r  = bih[gc]         + bhh[gc];
  const float b_z  = bih[gc + HID]   + bhh[gc + HID];
  const float b_in = bih[gc + 2*HID];
  const float b_hn = bhh[gc + 2*HID];
#pragma unroll
  for (int mt = 0; mt < 8; ++mt){
#pragma unroll
    for (int r = 0; r < 4; ++r){
      int grow = r0 + mt*16 + q*4 + r;
      float rr = sigmoid_f(accR[mt][r] + b_r);
      float u  = sigmoid_f(accZ[mt][r] + b_z);
      float nn = tanhf(accNi[mt][r] + b_in + rr*(accNh[mt][r] + b_hn));
      size_t idx = (size_t)grow*HID + gc;
      float hold = (float)hcur[idx];
      float hnew = (1.0f - u)*nn + u*hold;
      hnxt[idx] = (_Float16)hnew;
      if (hout) hout[idx] = hnew;
    }
  }
}

// ---------- fused out1 + tail + head: one block owns 16 env rows, all 512 o1 cols ----------
// o1 = relu(h[16x1024] @ w3T^T + b3)  (kept in fp32 regs)
// o  = tanh(o1 @ w4 + b4)  -> out[:, t, :]  and next state
// x2h(t+1) = relu(relu([o, z_{t+1}] @ w1 + b1) @ w2 + b2)
union OSM {
  half8 B[2][2048];                 // 64 KB: w3T staging, 2 x (512 cols x 4 segs)
  struct {
    float red[4][16][2];            // cross-wave tail partials
    float sts[16][2];
    float zs[16][64];
    float w1s[66*32];
    float x1s[16][32];
  } th;
};

__global__ __launch_bounds__(256, 1) void outtail_kernel(
    const _Float16* __restrict__ h16, const _Float16* __restrict__ w3T,
    const float* __restrict__ b3, const float* __restrict__ w4, const float* __restrict__ b4,
    const float* __restrict__ z,  const float* __restrict__ w1, const float* __restrict__ b1,
    const float* __restrict__ w2, const float* __restrict__ b2,
    _Float16* __restrict__ x2h, float* __restrict__ out, int t)
{
  __shared__ OSM sm;
  const int tid = threadIdx.x;
  const int lane = tid & 63, wave = tid >> 6;
  const int m = lane & 15, q = lane >> 4;
  const int r0 = blockIdx.x*16;

  // prefetch z_{t+1} rows for the head (HBM latency hides under the GEMM)
  f32x4 zreg = (f32x4){0.f,0.f,0.f,0.f};
  if (t < SEQ - 1)
    zreg = *(const f32x4*)(z + (size_t)(r0 + (tid >> 4))*SEQ*LATENT
                             + (size_t)(t + 1)*LATENT + (size_t)(tid & 15)*4);

  // A tile (16 rows x K=1024) straight to registers: 1 addr reg + imm offsets
  half8 areg[32];
  const _Float16* gA = h16 + (size_t)(r0 + m)*HID + q*8;
#pragma unroll
  for (int kb = 0; kb < 32; ++kb) areg[kb] = *(const half8*)(gA + kb*32);

  // B staging pointers: slot s = j*256 + tid -> col c = s>>2, phys seg p = s&3
  const _Float16* gB[8];
#pragma unroll
  for (int j = 0; j < 8; ++j){
    int s = j*256 + tid;
    int c = s >> 2, p = s & 3;
    gB[j] = w3T + (size_t)c*HID + seg_for_slot(c, p)*8;
  }

  auto issueB = [&](int bi){
    char* base = (char*)&sm.B[bi][0];
#pragma unroll
    for (int j = 0; j < 8; ++j){
      dma16(gB[j], base + (size_t)(j*256 + wave*64)*16);
      gB[j] += 32;
    }
  };

  issueB(0); issueB(1);

  f32x4 acc[8];
#pragma unroll
  for (int i = 0; i < 8; ++i) acc[i] = (f32x4){0.f,0.f,0.f,0.f};

#pragma unroll
  for (int it = 0; it < 32; ++it){
    if (it < 31) { WAITVM(8); } else { WAITVM(0); }
    BARRIER();
    const half8* bb = &sm.B[it & 1][0];
    half8 a = areg[it];
#pragma unroll
    for (int nt = 0; nt < 8; ++nt){
      half8 b = bb[phys_slot(wave*128 + nt*16 + m, q)];
      acc[nt] = mfma16(a, b, acc[nt]);
    }
    if (it + 2 < 32){
      BARRIER();                 // all waves done reading buf[it&1] before overwrite
      issueB(it & 1);
    }
  }
  __syncthreads();               // staging region free; overlay (th) becomes valid

  // tail: o1 = relu(acc + b3); partial o = o1 @ w4 over this wave's 128 cols
  float a0[4] = {0.f,0.f,0.f,0.f}, a1[4] = {0.f,0.f,0.f,0.f};
#pragma unroll
  for (int nt = 0; nt < 8; ++nt){
    int col = wave*128 + nt*16 + m;
    float b3v = b3[col];
    float w40 = w4[2*col], w41 = w4[2*col + 1];
#pragma unroll
    for (int r = 0; r < 4; ++r){
      float v = fmaxf(acc[nt][r] + b3v, 0.f);
      a0[r] += v*w40;
      a1[r] += v*w41;
    }
  }
#pragma unroll
  for (int r = 0; r < 4; ++r){
#pragma unroll
    for (int off = 1; off < 16; off <<= 1){
      a0[r] += __shfl_xor(a0[r], off);
      a1[r] += __shfl_xor(a1[r], off);
    }
  }
  if (m == 0){
#pragma unroll
    for (int r = 0; r < 4; ++r){
      sm.th.red[wave][q*4 + r][0] = a0[r];
      sm.th.red[wave][q*4 + r][1] = a1[r];
    }
  }
  if (t < SEQ - 1){
    *(f32x4*)&sm.th.zs[tid >> 4][(tid & 15)*4] = zreg;
    for (int i = tid; i < 66*32; i += 256) sm.th.w1s[i] = w1[i];
  }
  __syncthreads();

  if (tid < 16){
    int row = tid;
    float s0 = sm.th.red[0][row][0] + sm.th.red[1][row][0]
             + sm.th.red[2][row][0] + sm.th.red[3][row][0];
    float s1 = sm.th.red[0][row][1] + sm.th.red[1][row][1]
             + sm.th.red[2][row][1] + sm.th.red[3][row][1];
    s0 = tanhf(s0 + b4[0]);
    s1 = tanhf(s1 + b4[1]);
    out[(size_t)(r0 + row)*SEQ*SA + (size_t)t*SA + 0] = s0;
    out[(size_t)(r0 + row)*SEQ*SA + (size_t)t*SA + 1] = s1;
    sm.th.sts[row][0] = s0;
    sm.th.sts[row][1] = s1;
  }
  __syncthreads();

  if (t < SEQ - 1){
    // x1 = relu([state, z] @ w1 + b1): 16 rows x 32 cols
    for (int itr = tid; itr < 16*32; itr += 256){
      int r = itr >> 5, j = itr & 31;
      float acc1 = b1[j] + sm.th.sts[r][0]*sm.th.w1s[j] + sm.th.sts[r][1]*sm.th.w1s[32 + j];
#pragma unroll 8
      for (int k = 0; k < 64; ++k) acc1 += sm.th.zs[r][k]*sm.th.w1s[(k + 2)*32 + j];
      sm.th.x1s[r][j] = fmaxf(acc1, 0.f);
    }
    __syncthreads();
    // x2h = relu(x1 @ w2 + b2): 16 rows x 256 cols (one col per thread, w2 col in regs)
    float w2r[32];
#pragma unroll
    for (int k = 0; k < 32; ++k) w2r[k] = w2[k*256 + tid];
    float bb2 = b2[tid];
#pragma unroll 4
    for (int r = 0; r < 16; ++r){
      float acc2 = bb2;
#pragma unroll
      for (int k = 0; k < 32; ++k) acc2 += sm.th.x1s[r][k]*w2r[k];
      x2h[(size_t)(r0 + r)*EMB + tid] = (_Float16)fmaxf(acc2, 0.f);
    }
  }
}

// ---------- t=0 head: x2h from state=-2 and z_0 (runs once) ----------
__global__ void head0_kernel(const float* __restrict__ z, const float* __restrict__ w1,
                             const float* __restrict__ b1, const float* __restrict__ w2,
                             const float* __restrict__ b2, _Float16* __restrict__ x2h){
  __shared__ float w1s[66*32];
  __shared__ float zs[16][64];
  __shared__ float x1s[16][32];
  const int tid = threadIdx.x;
  const int r0 = blockIdx.x*16;
  for (int i = tid; i < 66*32; i += 256) w1s[i] = w1[i];
  for (int i = tid; i < 16*64; i += 256){
    int r = i >> 6, k = i & 63;
    zs[r][k] = z[(size_t)(r0 + r)*SEQ*LATENT + k];
  }
  __syncthreads();
  for (int itr = tid; itr < 16*32; itr += 256){
    int r = itr >> 5, j = itr & 31;
    float acc1 = b1[j] - 2.f*w1s[j] - 2.f*w1s[32 + j];
#pragma unroll 8
    for (int k = 0; k < 64; ++k) acc1 += zs[r][k]*w1s[(k + 2)*32 + j];
    x1s[r][j] = fmaxf(acc1, 0.f);
  }
  __syncthreads();
  float w2r[32];
#pragma unroll
  for (int k = 0; k < 32; ++k) w2r[k] = w2[k*256 + tid];
  float bb2 = b2[tid];
  for (int r = 0; r < 16; ++r){
    float acc2 = bb2;
#pragma unroll
    for (int k = 0; k < 32; ++k) acc2 += x1s[r][k]*w2r[k];
    x2h[(size_t)(r0 + r)*EMB + tid] = (_Float16)fmaxf(acc2, 0.f);
  }
}

extern "C" void kernel_launch(void* const* d_in, const int* in_sizes, int n_in,
                              void* d_out, int out_size, void* d_ws, size_t ws_size,
                              hipStream_t stream) {
  const float* z   = (const float*)d_in[0];
  const float* rnn = (const float*)d_in[1];
  const float* w1  = (const float*)d_in[2];
  const float* b1  = (const float*)d_in[3];
  const float* w2  = (const float*)d_in[4];
  const float* b2  = (const float*)d_in[5];
  const float* wih = (const float*)d_in[6];
  const float* bih = (const float*)d_in[7];
  const float* whh = (const float*)d_in[8];
  const float* bhh = (const float*)d_in[9];
  const float* w3  = (const float*)d_in[10];
  const float* b3  = (const float*)d_in[11];
  const float* w4  = (const float*)d_in[12];
  const float* b4  = (const float*)d_in[13];
  float* out = (float*)d_out;

  char* ws = (char*)d_ws;
  _Float16* wihT = (_Float16*)ws;                 ws += (size_t)3*HID*EMB*2;
  _Float16* whhT = (_Float16*)ws;                 ws += (size_t)3*HID*HID*2;
  _Float16* w3T  = (_Float16*)ws;                 ws += (size_t)(HID/2)*HID*2;
  _Float16* h16a = (_Float16*)ws;                 ws += (size_t)NENV*HID*2;
  _Float16* h16b = (_Float16*)ws;                 ws += (size_t)NENV*HID*2;
  _Float16* x2h  = (_Float16*)ws;                 ws += (size_t)NENV*EMB*2;

  transpose_cvt_kernel<<<512, 256, 0, stream>>>(wih, wihT, EMB, 3*HID);
  transpose_cvt_kernel<<<1024, 256, 0, stream>>>(whh, whhT, HID, 3*HID);
  transpose_cvt_kernel<<<256, 256, 0, stream>>>(w3, w3T, HID, HID/2);
  init_h_kernel<<<1024, 256, 0, stream>>>(rnn, h16a);

  head0_kernel<<<NENV/16, 256, 0, stream>>>(z, w1, b1, w2, b2, x2h);

  float* hfinal = out + (size_t)NENV*SEQ*SA;
  for (int t = 0; t < SEQ; ++t){
    _Float16* hc = (t & 1) ? h16b : h16a;
    _Float16* hn = (t & 1) ? h16a : h16b;
    gru_kernel<<<512, 256, 0, stream>>>(x2h, hc, wihT, whhT, bih, bhh, hn,
                                        (t == SEQ - 1) ? hfinal : nullptr);
    outtail_kernel<<<NENV/16, 256, 0, stream>>>(hn, w3T, b3, w4, b4, z, w1, b1, w2, b2,
                                                x2h, out, t);
  }
}

// Round 4
// 9986.656 us; speedup vs baseline: 2.3569x; 1.0586x over previous
//
#include <hip/hip_runtime.h>
#include <cstdint>
#include <cstddef>

#define NENV 4096
#define SEQ  128
#define LATENT 64
#define EMB  256
#define HID  1024
#define SA   2

typedef _Float16 half8 __attribute__((ext_vector_type(8)));
typedef float f32x4 __attribute__((ext_vector_type(4)));

// assembler-encoded partial drain: wait until <= n vector-mem ops outstanding
#define WAITVM(n) asm volatile("s_waitcnt vmcnt(" #n ")" ::: "memory")
#define BARRIER() { __builtin_amdgcn_s_barrier(); asm volatile("" ::: "memory"); }

__device__ __forceinline__ float sigmoid_f(float x){ return 1.0f/(1.0f + __expf(-x)); }

__device__ __forceinline__ void dma16(const void* g, void* l){
  __builtin_amdgcn_global_load_lds(
      (const __attribute__((address_space(1))) void*)g,
      (__attribute__((address_space(3))) void*)l, 16, 0, 0);
}

__device__ __forceinline__ f32x4 mfma16(half8 a, half8 b, f32x4 c){
  return __builtin_amdgcn_mfma_f32_16x16x32_f16(a, b, c, 0, 0, 0);
}

// bank swizzle: element [row R][seg s] lives at slot R*4 + ((s + R + (R>>2)) & 3)
// -> DMA slot R*4+p holds seg (p - R - (R>>2)) & 3   (same 64B line, permuted)
__device__ __forceinline__ int seg_for_slot(int R, int p){ return (p - R - (R >> 2)) & 3; }
__device__ __forceinline__ int phys_slot(int R, int q){ return R*4 + ((q + R + (R >> 2)) & 3); }

// ---------- pre-pass: transpose + fp32->fp16: in [K][C] -> out [C][K] ----------
__global__ void transpose_cvt_kernel(const float* __restrict__ in, _Float16* __restrict__ out,
                                     int K, int C){
  int n = K*C;
  for (int i = blockIdx.x*blockDim.x + threadIdx.x; i < n; i += gridDim.x*blockDim.x){
    int c = i / K;
    int k = i - c*K;
    out[i] = (_Float16)in[(size_t)k*C + c];
  }
}

__global__ void init_h_kernel(const float* __restrict__ rnn, _Float16* __restrict__ h16){
  int n = NENV*HID;
  for (int i = blockIdx.x*blockDim.x + threadIdx.x; i < n; i += gridDim.x*blockDim.x){
    h16[i] = (_Float16)rnn[i];
  }
}

// ---------- fused GRU: 128 rows x 64 h-cols x 3 gates, BK=32, pipelined depth-2 ----------
// buffer layout (slots of 16B): A[0..511] rows 0..127 x 4 segs; B[512 + g*256 + ...] 64 cols x 4 segs
// 3 buffers x 1280 slots = 60 KB.
template<int K, int NIT>
__device__ __forceinline__ void gru_phase(
    const _Float16* __restrict__ A, const _Float16* __restrict__ W,
    int r0, int c0, int tid, int wave,
    const int* pa, int pb, half8* sBuf,
    f32x4* accR, f32x4* accZ, f32x4* accN)
{
  const int RA0 = tid >> 2,        PA0 = tid & 3;
  const int RA1 = 64 + (tid >> 2), PA1 = tid & 3;
  const int RB  = tid >> 2,        PB  = tid & 3;
  const _Float16* gA0 = A + (size_t)(r0 + RA0)*K + seg_for_slot(RA0, PA0)*8;
  const _Float16* gA1 = A + (size_t)(r0 + RA1)*K + seg_for_slot(RA1, PA1)*8;
  const int sgb = seg_for_slot(RB, PB);
  const _Float16* gB0 = W + (size_t)(0*HID + c0 + RB)*K + sgb*8;
  const _Float16* gB1 = W + (size_t)(1*HID + c0 + RB)*K + sgb*8;
  const _Float16* gB2 = W + (size_t)(2*HID + c0 + RB)*K + sgb*8;

  auto issue = [&](int bi){
    char* base = (char*)sBuf + (size_t)bi*1280*16;
    dma16(gA0, base + (size_t)(0    + wave*64)*16);
    dma16(gA1, base + (size_t)(256  + wave*64)*16);
    dma16(gB0, base + (size_t)(512  + wave*64)*16);
    dma16(gB1, base + (size_t)(768  + wave*64)*16);
    dma16(gB2, base + (size_t)(1024 + wave*64)*16);
    gA0 += 32; gA1 += 32; gB0 += 32; gB1 += 32; gB2 += 32;
  };

  issue(0); issue(1);
#pragma unroll
  for (int it = 0; it < NIT; ++it){
    if (it < NIT - 1) { WAITVM(5); } else { WAITVM(0); }
    BARRIER();
    if (it + 2 < NIT) issue((it + 2) % 3);
    const half8* buf = sBuf + (it % 3)*1280;
    half8 b0 = buf[512  + pb];
    half8 b1 = buf[768  + pb];
    half8 b2 = buf[1024 + pb];
#pragma unroll
    for (int mt = 0; mt < 8; ++mt){
      half8 a = buf[pa[mt]];
      accR[mt] = mfma16(a, b0, accR[mt]);
      accZ[mt] = mfma16(a, b1, accZ[mt]);
      accN[mt] = mfma16(a, b2, accN[mt]);
    }
  }
  __syncthreads();   // all waves done with buffers before next phase reuses them
}

__global__ __launch_bounds__(256, 2) void gru_kernel(
    const _Float16* __restrict__ x2h, const _Float16* __restrict__ hcur,
    const _Float16* __restrict__ wihT, const _Float16* __restrict__ whhT,
    const float* __restrict__ bih, const float* __restrict__ bhh,
    _Float16* __restrict__ hnxt, float* __restrict__ hout)
{
  __shared__ half8 sBuf[3*1280];   // 60 KB
  const int tid = threadIdx.x;
  const int lane = tid & 63, wave = tid >> 6;
  const int m = lane & 15, q = lane >> 4, n0 = wave*16;

  // XCD swizzle: XCD x owns colgroups {2x, 2x+1} -> W slice L2-resident, h shared within XCD
  const int id = blockIdx.x;
  const int colg = (id & 7)*2 + ((id >> 3) & 1);
  const int rowg = id >> 4;            // 0..31
  const int r0 = rowg*128, c0 = colg*64;

  int pa[8];
#pragma unroll
  for (int mt = 0; mt < 8; ++mt) pa[mt] = phys_slot(mt*16 + m, q);
  const int pb = phys_slot(n0 + m, q);

  f32x4 accR[8], accZ[8], accNi[8], accNh[8];
#pragma unroll
  for (int i = 0; i < 8; ++i){
    accR[i] = (f32x4){0.f,0.f,0.f,0.f};
    accZ[i] = (f32x4){0.f,0.f,0.f,0.f};
    accNi[i] = (f32x4){0.f,0.f,0.f,0.f};
    accNh[i] = (f32x4){0.f,0.f,0.f,0.f};
  }

  gru_phase<EMB, EMB/32>(x2h,  wihT, r0, c0, tid, wave, pa, pb, sBuf, accR, accZ, accNi);
  gru_phase<HID, HID/32>(hcur, whhT, r0, c0, tid, wave, pa, pb, sBuf, accR, accZ, accNh);

  const int gc = c0 + n0 + m;
  const float b_r  = bih[gc]         + bhh[gc];
  const float b_z  = bih[gc + HID]   + bhh[gc + HID];
  const float b_in = bih[gc + 2*HID];
  const float b_hn = bhh[gc + 2*HID];
#pragma unroll
  for (int mt = 0; mt < 8; ++mt){
#pragma unroll
    for (int r = 0; r < 4; ++r){
      int grow = r0 + mt*16 + q*4 + r;
      float rr = sigmoid_f(accR[mt][r] + b_r);
      float u  = sigmoid_f(accZ[mt][r] + b_z);
      float nn = tanhf(accNi[mt][r] + b_in + rr*(accNh[mt][r] + b_hn));
      size_t idx = (size_t)grow*HID + gc;
      float hold = (float)hcur[idx];
      float hnew = (1.0f - u)*nn + u*hold;
      hnxt[idx] = (_Float16)hnew;
      if (hout) hout[idx] = hnew;
    }
  }
}

// ---------- o1 = relu(h @ w3 + b3) -> fp16, 64x64 tile, BK=32, pipelined ----------
__global__ __launch_bounds__(256, 4) void out1_kernel(
    const _Float16* __restrict__ h16, const _Float16* __restrict__ w3T,
    const float* __restrict__ b3, _Float16* __restrict__ o1)
{
  __shared__ half8 sBuf[3*512];    // 24 KB
  const int tid = threadIdx.x;
  const int lane = tid & 63, wave = tid >> 6;
  const int m = lane & 15, q = lane >> 4, n0 = wave*16;

  const int id = blockIdx.x;
  const int colg = id & 7;     // XCD x owns col slice x (w3T slice 128 KB L2-resident)
  const int rowg = id >> 3;    // 0..63
  const int r0 = rowg*64, c0 = colg*64;

  int pa[4];
#pragma unroll
  for (int mt = 0; mt < 4; ++mt) pa[mt] = phys_slot(mt*16 + m, q);
  const int pb = phys_slot(n0 + m, q);

  f32x4 acc[4];
#pragma unroll
  for (int i = 0; i < 4; ++i) acc[i] = (f32x4){0.f,0.f,0.f,0.f};

  const int R = tid >> 2, P = tid & 3;
  const int sg = seg_for_slot(R, P);
  const _Float16* gA = h16 + (size_t)(r0 + R)*HID + sg*8;
  const _Float16* gB = w3T + (size_t)(c0 + R)*HID + sg*8;

  auto issue = [&](int bi){
    char* base = (char*)sBuf + (size_t)bi*512*16;
    dma16(gA, base + (size_t)(0   + wave*64)*16);
    dma16(gB, base + (size_t)(256 + wave*64)*16);
    gA += 32; gB += 32;
  };

  issue(0); issue(1);
#pragma unroll
  for (int it = 0; it < 32; ++it){
    if (it < 31) { WAITVM(2); } else { WAITVM(0); }
    BARRIER();
    if (it + 2 < 32) issue((it + 2) % 3);
    const half8* buf = sBuf + (it % 3)*512;
    half8 b = buf[256 + pb];
#pragma unroll
    for (int mt = 0; mt < 4; ++mt){
      half8 a = buf[pa[mt]];
      acc[mt] = mfma16(a, b, acc[mt]);
    }
  }

  const int gc = c0 + n0 + m;
  const float bb = b3[gc];
#pragma unroll
  for (int mt = 0; mt < 4; ++mt){
#pragma unroll
    for (int r = 0; r < 4; ++r){
      int grow = r0 + mt*16 + q*4 + r;
      o1[(size_t)grow*(HID/2) + gc] = (_Float16)fmaxf(acc[mt][r] + bb, 0.f);
    }
  }
}

// ---------- tail of step t fused with head of step t+1 ----------
// mode 0: init (state=-2, x2 for t=0); mode 1: mid; mode 2: last (head only)
__global__ void tail_head_kernel(
    const _Float16* __restrict__ o1, const float* __restrict__ w4, const float* __restrict__ b4,
    const float* __restrict__ z,  const float* __restrict__ w1, const float* __restrict__ b1,
    const float* __restrict__ w2, const float* __restrict__ b2,
    _Float16* __restrict__ x2h, float* __restrict__ out, int t, int mode)
{
  __shared__ float sw2[32*256];   // 32 KB
  __shared__ float sw1[66*32];    // 8.4 KB
  __shared__ float sz[16][64];
  __shared__ float sx1[16][32];
  __shared__ float sst[16][2];
  const int tid = threadIdx.x;
  const int r0 = blockIdx.x*16;

  if (mode != 2){
    for (int i = tid; i < 66*32; i += 256) sw1[i] = w1[i];
    for (int i = tid; i < 32*256; i += 256) sw2[i] = w2[i];
    int zt = (mode == 0) ? 0 : (t + 1);
    for (int i = tid; i < 16*64; i += 256){
      int r = i >> 6, k = i & 63;
      sz[r][k] = z[(size_t)(r0 + r)*SEQ*LATENT + zt*LATENT + k];
    }
  }

  if (mode != 0){
    int r = tid >> 4, p = tid & 15;
    const _Float16* orow = o1 + (size_t)(r0 + r)*(HID/2);
    float a0 = 0.f, a1 = 0.f;
    for (int k = p*32; k < p*32 + 32; ++k){
      float v = (float)orow[k];
      a0 += v*w4[k*2];
      a1 += v*w4[k*2 + 1];
    }
#pragma unroll
    for (int off = 1; off < 16; off <<= 1){
      a0 += __shfl_xor(a0, off);
      a1 += __shfl_xor(a1, off);
    }
    if (p == 0){
      a0 = tanhf(a0 + b4[0]);
      a1 = tanhf(a1 + b4[1]);
      out[(size_t)(r0 + r)*SEQ*SA + t*SA + 0] = a0;
      out[(size_t)(r0 + r)*SEQ*SA + t*SA + 1] = a1;
      sst[r][0] = a0; sst[r][1] = a1;
    }
  } else {
    if (tid < 32) sst[tid >> 1][tid & 1] = -2.0f;
  }
  __syncthreads();

  if (mode != 2){
    for (int it = tid; it < 16*32; it += 256){
      int r = it >> 5, j = it & 31;
      float acc = b1[j];
      acc += sst[r][0]*sw1[0*32 + j] + sst[r][1]*sw1[1*32 + j];
#pragma unroll 8
      for (int k = 0; k < 64; ++k) acc += sz[r][k]*sw1[(k + 2)*32 + j];
      sx1[r][j] = fmaxf(acc, 0.f);
    }
    __syncthreads();
    int col = tid;
    for (int r = 0; r < 16; ++r){
      float acc = b2[col];
#pragma unroll
      for (int k = 0; k < 32; ++k) acc += sx1[r][k]*sw2[k*256 + col];
      x2h[(size_t)(r0 + r)*EMB + col] = (_Float16)fmaxf(acc, 0.f);
    }
  }
}

extern "C" void kernel_launch(void* const* d_in, const int* in_sizes, int n_in,
                              void* d_out, int out_size, void* d_ws, size_t ws_size,
                              hipStream_t stream) {
  const float* z   = (const float*)d_in[0];
  const float* rnn = (const float*)d_in[1];
  const float* w1  = (const float*)d_in[2];
  const float* b1  = (const float*)d_in[3];
  const float* w2  = (const float*)d_in[4];
  const float* b2  = (const float*)d_in[5];
  const float* wih = (const float*)d_in[6];
  const float* bih = (const float*)d_in[7];
  const float* whh = (const float*)d_in[8];
  const float* bhh = (const float*)d_in[9];
  const float* w3  = (const float*)d_in[10];
  const float* b3  = (const float*)d_in[11];
  const float* w4  = (const float*)d_in[12];
  const float* b4  = (const float*)d_in[13];
  float* out = (float*)d_out;

  char* ws = (char*)d_ws;
  _Float16* wihT = (_Float16*)ws;                 ws += (size_t)3*HID*EMB*2;
  _Float16* whhT = (_Float16*)ws;                 ws += (size_t)3*HID*HID*2;
  _Float16* w3T  = (_Float16*)ws;                 ws += (size_t)(HID/2)*HID*2;
  _Float16* h16a = (_Float16*)ws;                 ws += (size_t)NENV*HID*2;
  _Float16* h16b = (_Float16*)ws;                 ws += (size_t)NENV*HID*2;
  _Float16* x2h  = (_Float16*)ws;                 ws += (size_t)NENV*EMB*2;
  _Float16* o1   = (_Float16*)ws;                 ws += (size_t)NENV*(HID/2)*2;

  transpose_cvt_kernel<<<512, 256, 0, stream>>>(wih, wihT, EMB, 3*HID);
  transpose_cvt_kernel<<<1024, 256, 0, stream>>>(whh, whhT, HID, 3*HID);
  transpose_cvt_kernel<<<256, 256, 0, stream>>>(w3, w3T, HID, HID/2);
  init_h_kernel<<<1024, 256, 0, stream>>>(rnn, h16a);

  tail_head_kernel<<<NENV/16, 256, 0, stream>>>(o1, w4, b4, z, w1, b1, w2, b2, x2h, out, 0, 0);

  float* hfinal = out + (size_t)NENV*SEQ*SA;
  for (int t = 0; t < SEQ; ++t){
    _Float16* hc = (t & 1) ? h16b : h16a;
    _Float16* hn = (t & 1) ? h16a : h16b;
    gru_kernel<<<512, 256, 0, stream>>>(x2h, hc, wihT, whhT, bih, bhh, hn,
                                        (t == SEQ - 1) ? hfinal : nullptr);
    out1_kernel<<<512, 256, 0, stream>>>(hn, w3T, b3, o1);
    tail_head_kernel<<<NENV/16, 256, 0, stream>>>(o1, w4, b4, z, w1, b1, w2, b2, x2h, out,
                                                  t, (t < SEQ - 1) ? 1 : 2);
  }
}